// Round 4
// baseline (252.564 us; speedup 1.0000x reference)
//
#include <hip/hip_runtime.h>

#define NROWS   262144
#define DCOLS   128
#define NBLOCKS 2048
#define MARGIN_SQ 0.390625f   // (1.25/2)^2

// Native clang vector type (true vector pointee for __builtin_nontemporal_load).
typedef float v4f __attribute__((ext_vector_type(4)));

// ROUND-4: explicit 2-deep double-buffered load pipeline.
// Evidence: rounds 1-2 showed VGPR_Count=36 -> compiler collapsed the load
// batch to pipeline depth ~1-2 (issue 2 loads, drain vmcnt, 30-cycle shfl
// chain, repeat). That issue-gap pattern explains the ~4.0 TB/s read plateau
// (vs 6.3+ TB/s the fill sustains). Here: 4 row-pairs (8 x 1KB NT loads)
// per batch, two NAMED register buffers (static indexing only -- runtime
// indexing would spill to scratch), next batch issued BEFORE computing the
// current one. Steady state keeps 8-16KB outstanding per wave with partial
// vmcnt waits.
//
// desire: ONE coalesced dword load per wave (lane l -> desire[r0+(l&31)]).
// Keeps small loads out of the vmcnt ordering of the 1KB loads. Each lane
// accumulates act/inter EXACTLY ONCE for "its" row via a predicate
// (row 2p -> lane 2p in lower half; row 2p+1 -> lane 32+2p+1 in upper half),
// so no redundancy scaling and no cross-lane desire fetch is needed.
//
// Layout per wave: 32 consecutive rows (16 row-pairs); one instruction reads
// one full 1KB row-pair (lane l -> bytes [16l,16l+16)). Butterfly xor 1..16
// stays within each 32-lane half = one row.

#define LOADB(da, db, pb)                                                   \
  {                                                                         \
    _Pragma("unroll")                                                       \
    for (int k = 0; k < 4; k++) {                                           \
      da[k] = __builtin_nontemporal_load(&a[((pb) * 4 + k) * 64 + lane]);   \
      db[k] = __builtin_nontemporal_load(&b[((pb) * 4 + k) * 64 + lane]);   \
    }                                                                       \
  }

#define COMPB(sa, sb, pb)                                                   \
  {                                                                         \
    _Pragma("unroll")                                                       \
    for (int k = 0; k < 4; k++) {                                           \
      const int p = (pb) * 4 + k;                                           \
      const v4f df = sa[k] - sb[k];                                         \
      float s = df.x * df.x + df.y * df.y + df.z * df.z + df.w * df.w;      \
      s += __shfl_xor(s, 1);                                                \
      s += __shfl_xor(s, 2);                                                \
      s += __shfl_xor(s, 4);                                                \
      s += __shfl_xor(s, 8);                                                \
      s += __shfl_xor(s, 16);                                               \
      const float act = (s > MARGIN_SQ) ? 1.0f : 0.0f;                      \
      const float sel = ((lane & 31) == 2 * p + h) ? 1.0f : 0.0f;           \
      l_act   += act * sel;                                                 \
      l_inter += act * dv * sel;                                            \
    }                                                                       \
  }

__global__ __launch_bounds__(256) void fra_main(const float* __restrict__ o1,
                                                const float* __restrict__ o2,
                                                const float* __restrict__ desire,
                                                float* __restrict__ ws) {
    __shared__ float s_inter[4], s_act[4], s_des[4];
    const int tid  = threadIdx.x;
    const int lane = tid & 63;
    const int wave = tid >> 6;                 // 0..3
    const int h    = lane >> 5;                // row within the pair
    const int wgid = blockIdx.x * 4 + wave;    // 0..8191
    const int r0   = wgid * 32;                // 32 rows per wave, exact cover

    const v4f* __restrict__ a = (const v4f*)(o1 + (size_t)r0 * DCOLS);
    const v4f* __restrict__ b = (const v4f*)(o2 + (size_t)r0 * DCOLS);

    // One coalesced desire load per wave: lane l holds desire[r0 + (l&31)].
    const float dv = desire[r0 + (lane & 31)];

    float l_inter = 0.0f, l_act = 0.0f;

    v4f vaA[4], vbA[4], vaB[4], vbB[4];

    // Prologue: fill both buffers (16 loads = 16KB in flight).
    LOADB(vaA, vbA, 0);
    LOADB(vaB, vbB, 1);

    // Steady state: compute one buffer while the other's loads are in flight,
    // refilling it before the next compute. Partial vmcnt waits, never drains.
    COMPB(vaA, vbA, 0);
    LOADB(vaA, vbA, 2);
    COMPB(vaB, vbB, 1);
    LOADB(vaB, vbB, 3);
    COMPB(vaA, vbA, 2);
    COMPB(vaB, vbB, 3);

    // l_inter / l_act are exact per-lane partials (each row counted once
    // across the wave). desire row-sum = butterfly(dv) / 2 (each row's value
    // is present in both halves).
    float l_des = dv;
    #pragma unroll
    for (int off = 1; off <= 32; off <<= 1) {
        l_inter += __shfl_xor(l_inter, off);
        l_act   += __shfl_xor(l_act,   off);
        l_des   += __shfl_xor(l_des,   off);
    }

    if (lane == 0) {
        s_inter[wave] = l_inter;
        s_act[wave]   = l_act;
        s_des[wave]   = l_des * 0.5f;
    }
    __syncthreads();
    if (tid == 0) {
        ws[blockIdx.x]               = s_inter[0] + s_inter[1] + s_inter[2] + s_inter[3];
        ws[NBLOCKS + blockIdx.x]     = s_act[0]   + s_act[1]   + s_act[2]   + s_act[3];
        ws[2 * NBLOCKS + blockIdx.x] = s_des[0]   + s_des[1]   + s_des[2]   + s_des[3];
    }
}

__global__ __launch_bounds__(1024) void fra_reduce(const float* __restrict__ ws,
                                                   float* __restrict__ out) {
    __shared__ float s[3][16];
    const int t = threadIdx.x;
    float i = ws[t]        + ws[t + 1024];
    float a = ws[2048 + t] + ws[2048 + t + 1024];
    float d = ws[4096 + t] + ws[4096 + t + 1024];

    #pragma unroll
    for (int off = 32; off >= 1; off >>= 1) {
        i += __shfl_xor(i, off);
        a += __shfl_xor(a, off);
        d += __shfl_xor(d, off);
    }
    const int lane = t & 63, w = t >> 6;
    if (lane == 0) { s[0][w] = i; s[1][w] = a; s[2][w] = d; }
    __syncthreads();
    if (t == 0) {
        float ti = 0.0f, ta = 0.0f, td = 0.0f;
        #pragma unroll
        for (int k = 0; k < 16; k++) { ti += s[0][k]; ta += s[1][k]; td += s[2][k]; }
        const float uni = ta + td - ti;
        out[0] = (ti + 1e-6f) / (uni + 1e-6f);
    }
}

extern "C" void kernel_launch(void* const* d_in, const int* in_sizes, int n_in,
                              void* d_out, int out_size, void* d_ws, size_t ws_size,
                              hipStream_t stream) {
    const float* o1     = (const float*)d_in[0];
    const float* o2     = (const float*)d_in[1];
    const float* desire = (const float*)d_in[2];
    float*       out    = (float*)d_out;
    float*       ws     = (float*)d_ws;

    fra_main<<<NBLOCKS, 256, 0, stream>>>(o1, o2, desire, ws);
    fra_reduce<<<1, 1024, 0, stream>>>(ws, out);
}